// Round 1
// baseline (6631.156 us; speedup 1.0000x reference)
//
#include <hip/hip_runtime.h>
#include <cstddef>
#include <cstdint>

// VisionExperts: 3 vision towers (patch-embed GEMM) + feature resize + projector GEMM,
// combined with per-sample routing weights. All fp32 (no fp32 MFMA on CDNA4 -> vector ALU GEMM).
//
// Expert configs: (S=img, P=patch, C=chan, G=S/P, T=G*G, K=3*P*P)
//   E0: 448,14,1024,32,1024,588   (no input resize, no feature resize)
//   E1: 336,14, 768,24, 576,588   (input 448->336, feature 24->32)
//   E2: 448,32,1152,14, 196,3072  (no input resize, feature 14->32)

#define HID 1024

// ---------------------------------------------------------------- weights
__global__ void k_weights(const int* __restrict__ sel, const float* __restrict__ rw,
                          float* __restrict__ w3) {
  int b = threadIdx.x;
  if (b < 64) {
    float w0 = 0.f, w1 = 0.f, w2 = 0.f;
    for (int k = 0; k < 2; ++k) {
      int e = sel[b * 2 + k];
      float r = rw[b * 2 + k];
      if (e == 0) w0 += r; else if (e == 1) w1 += r; else w2 += r;
    }
    w3[b * 3 + 0] = w0; w3[b * 3 + 1] = w1; w3[b * 3 + 2] = w2;
  }
}

// ---------------------------------------------------------------- tables
// koff[k] : offset of patch-element k within one sample image (k = ch*P*P + py*P + px)
// rowoff[m]: offset of patch (bl,gy,gx) top-left within chunk (m = bl*T + gy*G + gx)
// stok/wco : bilinear source tokens + weights for feature-grid resize G->32 (align_corners)
__global__ void k_tables(int* __restrict__ koff, int* __restrict__ rowoff,
                         int4* __restrict__ stok, float4* __restrict__ wco,
                         int S, int P, int G, int T, int bch) {
  int idx = blockIdx.x * 256 + threadIdx.x;
  int K = 3 * P * P;
  if (idx < K) {
    int pp = P * P;
    int ch = idx / pp;
    int r = idx - ch * pp;
    int py = r / P;
    int px = r - py * P;
    koff[idx] = ch * S * S + py * S + px;
  }
  int nro = bch * T;
  if (idx < nro) {
    int bl = idx / T;
    int t = idx - bl * T;
    int gy = t / G;
    int gx = t - gy * G;
    rowoff[idx] = bl * 3 * S * S + gy * P * S + gx * P;
  }
  if (idx < 1024) {
    int oy = idx >> 5, ox = idx & 31;
    float sc = (float)(G - 1) / 31.0f;
    float fy = oy * sc, fx = ox * sc;
    int y0 = (int)floorf(fy), x0 = (int)floorf(fx);
    float ty = fy - y0, tx = fx - x0;
    int y1 = min(y0 + 1, G - 1), x1 = min(x0 + 1, G - 1);
    stok[idx] = make_int4(y0 * G + x0, y0 * G + x1, y1 * G + x0, y1 * G + x1);
    wco[idx] = make_float4((1.f - ty) * (1.f - tx), (1.f - ty) * tx,
                           ty * (1.f - tx), ty * tx);
  }
}

// ---------------------------------------------------------------- input resize 448->336 (align_corners)
__global__ void k_resize_img(const float* __restrict__ x, float* __restrict__ o, int total) {
  int idx = blockIdx.x * 256 + threadIdx.x;
  if (idx >= total) return;
  int ox = idx % 336;
  int t = idx / 336;
  int oy = t % 336;
  int bc = t / 336;  // bl*3 + ch
  const float sc = 447.0f / 335.0f;
  float fy = oy * sc, fx = ox * sc;
  int y0 = (int)floorf(fy), x0 = (int)floorf(fx);
  float ty = fy - y0, tx = fx - x0;
  int y1 = min(y0 + 1, 447), x1 = min(x0 + 1, 447);
  const float* p = x + (size_t)bc * 448 * 448;
  float v00 = p[y0 * 448 + x0], v01 = p[y0 * 448 + x1];
  float v10 = p[y1 * 448 + x0], v11 = p[y1 * 448 + x1];
  float r0 = v00 * (1.f - ty) + v10 * ty;
  float r1 = v01 * (1.f - ty) + v11 * ty;
  o[idx] = r0 * (1.f - tx) + r1 * tx;
}

// ---------------------------------------------------------------- tower GEMM (gathered A)
// C[m,n] = sum_k xsrc[rowoff[m]+koff[k]] * W[k,n] + bias[n]
// 128x128 block tile, BK=16, 256 threads, 8x8 microtile (split 4+4 with 64 stride).
__global__ __launch_bounds__(256, 2) void k_gemm_tower(
    const float* __restrict__ xsrc, const int* __restrict__ rowoff,
    const int* __restrict__ koff, const float* __restrict__ W,
    const float* __restrict__ bias, float* __restrict__ C,
    int M, int N, int K) {
  extern __shared__ float smem[];
  float(*As)[132] = (float(*)[132])smem;              // [16][132]
  float(*Bs)[132] = (float(*)[132])(smem + 16 * 132); // [16][132]
  int* koffs = (int*)(smem + 2 * 16 * 132);

  int tid = threadIdx.x;
  int KT = (K + 15) >> 4;
  int Kp = KT << 4;
  for (int k = tid; k < Kp; k += 256) koffs[k] = (k < K) ? koff[k] : 0;

  int n0 = blockIdx.x * 128;
  int m0 = blockIdx.y * 128;
  int a_mm = tid & 127;
  int a_k8 = (tid >> 7) << 3;  // 0 or 8
  int a_row = m0 + a_mm;
  int a_ro = (a_row < M) ? rowoff[a_row] : -1;
  int b_kk = tid >> 5;          // 0..7
  int b_nn = (tid & 31) << 2;   // 0..124
  int tn = (tid & 15) << 2;     // col base
  int tmq = (tid >> 4) << 2;    // row base

  float acc[8][8] = {};
  __syncthreads();  // koffs ready

  for (int kt = 0; kt < KT; ++kt) {
    int k0 = kt << 4;
    float a_reg[8];
#pragma unroll
    for (int j = 0; j < 8; ++j) {
      int k = k0 + a_k8 + j;
      a_reg[j] = (a_ro >= 0 && k < K) ? xsrc[a_ro + koffs[k]] : 0.f;
    }
    float4 b0 = make_float4(0.f, 0.f, 0.f, 0.f);
    float4 b1 = make_float4(0.f, 0.f, 0.f, 0.f);
    int kb0 = k0 + b_kk, kb1 = kb0 + 8;
    if (kb0 < K) b0 = *(const float4*)&W[(size_t)kb0 * N + n0 + b_nn];
    if (kb1 < K) b1 = *(const float4*)&W[(size_t)kb1 * N + n0 + b_nn];
    __syncthreads();
#pragma unroll
    for (int j = 0; j < 8; ++j) As[a_k8 + j][a_mm] = a_reg[j];
    *(float4*)&Bs[b_kk][b_nn] = b0;
    *(float4*)&Bs[b_kk + 8][b_nn] = b1;
    __syncthreads();
#pragma unroll
    for (int kk = 0; kk < 16; ++kk) {
      float4 a0 = *(const float4*)&As[kk][tmq];
      float4 a1 = *(const float4*)&As[kk][tmq + 64];
      float4 v0 = *(const float4*)&Bs[kk][tn];
      float4 v1 = *(const float4*)&Bs[kk][tn + 64];
      float ar[8] = {a0.x, a0.y, a0.z, a0.w, a1.x, a1.y, a1.z, a1.w};
      float br[8] = {v0.x, v0.y, v0.z, v0.w, v1.x, v1.y, v1.z, v1.w};
#pragma unroll
      for (int i = 0; i < 8; ++i)
#pragma unroll
        for (int j = 0; j < 8; ++j) acc[i][j] += ar[i] * br[j];
    }
  }

#pragma unroll
  for (int ih = 0; ih < 2; ++ih)
#pragma unroll
    for (int i = 0; i < 4; ++i) {
      int m = m0 + tmq + ih * 64 + i;
      if (m >= M) continue;
      float* cp = C + (size_t)m * N + n0;
#pragma unroll
      for (int jh = 0; jh < 2; ++jh) {
        int nn = tn + jh * 64;
        float4 v;
        v.x = acc[ih * 4 + i][jh * 4 + 0] + bias[n0 + nn + 0];
        v.y = acc[ih * 4 + i][jh * 4 + 1] + bias[n0 + nn + 1];
        v.z = acc[ih * 4 + i][jh * 4 + 2] + bias[n0 + nn + 2];
        v.w = acc[ih * 4 + i][jh * 4 + 3] + bias[n0 + nn + 3];
        *(float4*)&cp[nn] = v;
      }
    }
}

// ---------------------------------------------------------------- feature-grid bilinear resize
// F[bl, t, c] = sum_j wco[t][j] * C1[bl, stok[t][j], c]
__global__ void k_feat_resize(const float* __restrict__ C1, float* __restrict__ F,
                              const int4* __restrict__ stok, const float4* __restrict__ wco,
                              int Tsrc, int C) {
  int bt = blockIdx.x;
  int bl = bt >> 10, t = bt & 1023;
  int4 s = stok[t];
  float4 w = wco[t];
  const float* base = C1 + (size_t)bl * Tsrc * C;
  float* o = F + (size_t)bt * C;
  for (int c = threadIdx.x; c < C; c += 256) {
    o[c] = w.x * base[s.x * C + c] + w.y * base[s.y * C + c] +
           w.z * base[s.z * C + c] + w.w * base[s.w * C + c];
  }
}

// ---------------------------------------------------------------- projector GEMM + weighted accumulate
// out[b0*1024 + m, n] += wgt * (A[m,:] @ W[:,n] + bias[n]); whole block skips if wgt==0 (exact).
// M = bch*1024 (div by 128), N = 1024, K in {1024,768,1152} (div by 16).
__global__ __launch_bounds__(256, 2) void k_gemm_proj(
    const float* __restrict__ A, const float* __restrict__ W,
    const float* __restrict__ bias, float* __restrict__ out,
    const float* __restrict__ w3, int b0, int e, int K) {
  __shared__ float As[16][132];
  __shared__ float Bs[16][132];
  int tid = threadIdx.x;
  int n0 = blockIdx.x * 128;
  int m0 = blockIdx.y * 128;
  int bl = m0 >> 10;  // 128 | 1024 -> tile within one sample
  float wgt = w3[(b0 + bl) * 3 + e];
  if (wgt == 0.0f) return;  // uniform across block; exact skip of out += 0

  int a_mm = tid >> 2;          // 0..63
  int a_k4 = (tid & 3) << 2;    // 0,4,8,12
  int b_kk = tid >> 5;
  int b_nn = (tid & 31) << 2;
  int tn = (tid & 15) << 2;
  int tmq = (tid >> 4) << 2;
  const float* Ap = A + (size_t)m0 * K;
  float acc[8][8] = {};
  int KT = K >> 4;

  for (int kt = 0; kt < KT; ++kt) {
    int k0 = kt << 4;
    float4 a0 = *(const float4*)&Ap[(size_t)a_mm * K + k0 + a_k4];
    float4 a1 = *(const float4*)&Ap[(size_t)(a_mm + 64) * K + k0 + a_k4];
    float4 bq0 = *(const float4*)&W[(size_t)(k0 + b_kk) * HID + n0 + b_nn];
    float4 bq1 = *(const float4*)&W[(size_t)(k0 + b_kk + 8) * HID + n0 + b_nn];
    __syncthreads();
    As[a_k4 + 0][a_mm] = a0.x; As[a_k4 + 1][a_mm] = a0.y;
    As[a_k4 + 2][a_mm] = a0.z; As[a_k4 + 3][a_mm] = a0.w;
    As[a_k4 + 0][a_mm + 64] = a1.x; As[a_k4 + 1][a_mm + 64] = a1.y;
    As[a_k4 + 2][a_mm + 64] = a1.z; As[a_k4 + 3][a_mm + 64] = a1.w;
    *(float4*)&Bs[b_kk][b_nn] = bq0;
    *(float4*)&Bs[b_kk + 8][b_nn] = bq1;
    __syncthreads();
#pragma unroll
    for (int kk = 0; kk < 16; ++kk) {
      float4 x0 = *(const float4*)&As[kk][tmq];
      float4 x1 = *(const float4*)&As[kk][tmq + 64];
      float4 y0 = *(const float4*)&Bs[kk][tn];
      float4 y1 = *(const float4*)&Bs[kk][tn + 64];
      float ar[8] = {x0.x, x0.y, x0.z, x0.w, x1.x, x1.y, x1.z, x1.w};
      float br[8] = {y0.x, y0.y, y0.z, y0.w, y1.x, y1.y, y1.z, y1.w};
#pragma unroll
      for (int i = 0; i < 8; ++i)
#pragma unroll
        for (int j = 0; j < 8; ++j) acc[i][j] += ar[i] * br[j];
    }
  }

  const float* bpn = bias + n0;
  float* obase = out + ((size_t)b0 * 1024 + (size_t)m0) * HID + n0;
#pragma unroll
  for (int ih = 0; ih < 2; ++ih)
#pragma unroll
    for (int i = 0; i < 4; ++i) {
      int r = tmq + ih * 64 + i;
      float* op = obase + (size_t)r * HID;
#pragma unroll
      for (int jh = 0; jh < 2; ++jh) {
        int nn = tn + jh * 64;
        float4 cur = *(const float4*)&op[nn];
        cur.x += wgt * (acc[ih * 4 + i][jh * 4 + 0] + bpn[nn + 0]);
        cur.y += wgt * (acc[ih * 4 + i][jh * 4 + 1] + bpn[nn + 1]);
        cur.z += wgt * (acc[ih * 4 + i][jh * 4 + 2] + bpn[nn + 2]);
        cur.w += wgt * (acc[ih * 4 + i][jh * 4 + 3] + bpn[nn + 3]);
        *(float4*)&op[nn] = cur;
      }
    }
}

// ---------------------------------------------------------------- launch
extern "C" void kernel_launch(void* const* d_in, const int* in_sizes, int n_in,
                              void* d_out, int out_size, void* d_ws, size_t ws_size,
                              hipStream_t stream) {
  (void)in_sizes; (void)n_in;
  const float* x = (const float*)d_in[0];
  const int* sel = (const int*)d_in[1];
  const float* rw = (const float*)d_in[2];
  const float* wt[3] = {(const float*)d_in[3], (const float*)d_in[7], (const float*)d_in[11]};
  const float* bt[3] = {(const float*)d_in[4], (const float*)d_in[8], (const float*)d_in[12]};
  const float* wp[3] = {(const float*)d_in[5], (const float*)d_in[9], (const float*)d_in[13]};
  const float* bp[3] = {(const float*)d_in[6], (const float*)d_in[10], (const float*)d_in[14]};
  float* out = (float*)d_out;

  char* ws = (char*)d_ws;
  size_t off = 0;
  auto alloc = [&](size_t bytes) -> void* {
    off = (off + 255) & ~(size_t)255;
    void* p = ws + off;
    off += bytes;
    return p;
  };

  float* w3 = (float*)alloc(64 * 3 * 4);
  int* koff0 = (int*)alloc(588 * 4);
  int* koff1 = (int*)alloc(588 * 4);
  int* koff2 = (int*)alloc(3072 * 4);
  int* ro0 = (int*)alloc((size_t)64 * 1024 * 4);  // sized for bch up to 64
  int* ro1 = (int*)alloc((size_t)64 * 576 * 4);
  int* ro2 = (int*)alloc((size_t)64 * 196 * 4);
  int4* st1 = (int4*)alloc(1024 * 16);
  float4* wc1 = (float4*)alloc(1024 * 16);
  int4* st2 = (int4*)alloc(1024 * 16);
  float4* wc2 = (float4*)alloc(1024 * 16);
  size_t tab_end = off;

  // pick batch-chunk size that fits the workspace (deterministic in ws_size -> graph-safe)
  const size_t per_b = ((size_t)3 * 336 * 336 + (size_t)1024 * 1024 + (size_t)1024 * 1152) * 4;
  int bch = 64;
  while (bch > 1 && tab_end + (size_t)bch * per_b + 4096 > ws_size) bch >>= 1;
  float* x336 = (float*)alloc((size_t)bch * 3 * 336 * 336 * 4);
  float* C1 = (float*)alloc((size_t)bch * 1024 * 1024 * 4);
  float* F = (float*)alloc((size_t)bch * 1024 * 1152 * 4);

  hipMemsetAsync(d_out, 0, (size_t)out_size * sizeof(float), stream);
  k_weights<<<1, 64, 0, stream>>>(sel, rw, w3);
  {
    int n0 = max(588, max(bch * 1024, 1024));
    int n1 = max(588, max(bch * 576, 1024));
    int n2 = max(3072, max(bch * 196, 1024));
    k_tables<<<(n0 + 255) / 256, 256, 0, stream>>>(koff0, ro0, st1, wc1, 448, 14, 32, 1024, bch);
    // note: st/wc for E0 unused (identity resize); reuse st1/wc1 slot harmlessly, then overwrite:
    k_tables<<<(n1 + 255) / 256, 256, 0, stream>>>(koff1, ro1, st1, wc1, 336, 14, 24, 576, bch);
    k_tables<<<(n2 + 255) / 256, 256, 0, stream>>>(koff2, ro2, st2, wc2, 448, 32, 14, 196, bch);
  }

  int nchunk = 64 / bch;
  for (int c = 0; c < nchunk; ++c) {
    int b0 = c * bch;
    const float* xc = x + (size_t)b0 * 3 * 448 * 448;
    dim3 gp(HID / 128, bch * 1024 / 128);

    // ---- Expert 0: tower (K=588) -> C1 is already the 32x32 grid -> proj
    {
      int M = bch * 1024, N = 1024, K = 588;
      int KT = (K + 15) / 16;
      size_t sh = 2 * 16 * 132 * 4 + (size_t)KT * 16 * 4;
      dim3 g(N / 128, (M + 127) / 128);
      k_gemm_tower<<<g, 256, sh, stream>>>(xc, ro0, koff0, wt[0], bt[0], C1, M, N, K);
      k_gemm_proj<<<gp, 256, 0, stream>>>(C1, wp[0], bp[0], out, w3, b0, 0, 1024);
    }
    // ---- Expert 1: resize img -> tower -> feat resize 24->32 -> proj
    {
      int tot = bch * 3 * 336 * 336;
      k_resize_img<<<(tot + 255) / 256, 256, 0, stream>>>(xc, x336, tot);
      int M = bch * 576, N = 768, K = 588;
      int KT = (K + 15) / 16;
      size_t sh = 2 * 16 * 132 * 4 + (size_t)KT * 16 * 4;
      dim3 g(N / 128, (M + 127) / 128);
      k_gemm_tower<<<g, 256, sh, stream>>>(x336, ro1, koff1, wt[1], bt[1], C1, M, N, K);
      k_feat_resize<<<bch * 1024, 256, 0, stream>>>(C1, F, st1, wc1, 576, 768);
      k_gemm_proj<<<gp, 256, 0, stream>>>(F, wp[1], bp[1], out, w3, b0, 1, 768);
    }
    // ---- Expert 2: tower (K=3072) -> feat resize 14->32 -> proj
    {
      int M = bch * 196, N = 1152, K = 3072;
      int KT = K / 16;
      size_t sh = 2 * 16 * 132 * 4 + (size_t)KT * 16 * 4;
      dim3 g(N / 128, (M + 127) / 128);
      k_gemm_tower<<<g, 256, sh, stream>>>(xc, ro2, koff2, wt[2], bt[2], C1, M, N, K);
      k_feat_resize<<<bch * 1024, 256, 0, stream>>>(C1, F, st2, wc2, 196, 1152);
      k_gemm_proj<<<gp, 256, 0, stream>>>(F, wp[2], bp[2], out, w3, b0, 2, 1152);
    }
  }
}

// Round 2
// 2325.000 us; speedup vs baseline: 2.8521x; 2.8521x over previous
//
#include <hip/hip_runtime.h>
#include <cstddef>
#include <cstdint>

// VisionExperts on MI355X — bf16 MFMA rewrite (m97-style 128x128/BK=32 tiles).
//   E0: S=448 P=14 C=1024 G=32 T=1024 K=588->Kp608   (no resizes)
//   E1: S=336 P=14 C=768  G=24 T=576  K=588->Kp608   (img 448->336, feat 24->32)
//   E2: S=448 P=32 C=1152 G=14 T=196  K=3072         (feat 14->32; A-staging via DMA)
// Weights pre-transposed to [N][Kp] bf16 (DMA-ready); images pre-converted to bf16;
// towers emit bf16 features [token][chan]; projector A+B both DMA-staged.

#define HID 1024

typedef __bf16 bf16x8 __attribute__((ext_vector_type(8)));
typedef float f32x4 __attribute__((ext_vector_type(4)));

__device__ __forceinline__ unsigned short f2bf(float f) {
  union { float f; unsigned u; } v; v.f = f;
  unsigned r = v.u + 0x7fffu + ((v.u >> 16) & 1u);  // RNE
  return (unsigned short)(r >> 16);
}
__device__ __forceinline__ float bf2f(unsigned h) {
  union { unsigned u; float f; } v; v.u = h << 16;
  return v.f;
}
__device__ __forceinline__ void gld16(const unsigned short* g, unsigned short* l) {
  auto gp = (const __attribute__((address_space(1))) unsigned int*)(const void*)g;
  auto lp = (__attribute__((address_space(3))) unsigned int*)(void*)l;
  __builtin_amdgcn_global_load_lds(gp, lp, 16, 0, 0);
}

// ---------------------------------------------------------------- small prep kernels
__global__ void k_weights(const int* __restrict__ sel, const float* __restrict__ rw,
                          float* __restrict__ w3) {
  int b = threadIdx.x;
  if (b < 64) {
    float w0 = 0.f, w1 = 0.f, w2 = 0.f;
    for (int k = 0; k < 2; ++k) {
      int e = sel[b * 2 + k];
      float r = rw[b * 2 + k];
      if (e == 0) w0 += r; else if (e == 1) w1 += r; else w2 += r;
    }
    w3[b * 3 + 0] = w0; w3[b * 3 + 1] = w1; w3[b * 3 + 2] = w2;
  }
}

__global__ void k_tables(int* __restrict__ koff, int* __restrict__ rowoff,
                         int4* __restrict__ stok, float4* __restrict__ wco,
                         int S, int P, int G, int T, int bch, int K, int Kp) {
  int idx = blockIdx.x * 256 + threadIdx.x;
  if (idx < Kp) {
    if (idx < K) {
      int pp = P * P;
      int ch = idx / pp;
      int r = idx - ch * pp;
      int py = r / P;
      int px = r - py * P;
      koff[idx] = ch * S * S + py * S + px;
    } else koff[idx] = 0;
  }
  int nro = bch * T;
  if (idx < nro) {
    int bl = idx / T;
    int t = idx - bl * T;
    int gy = t / G;
    int gx = t - gy * G;
    rowoff[idx] = bl * 3 * S * S + gy * P * S + gx * P;
  }
  if (idx < 1024) {
    int oy = idx >> 5, ox = idx & 31;
    float sc = (float)(G - 1) / 31.0f;
    float fy = oy * sc, fx = ox * sc;
    int y0 = (int)floorf(fy), x0 = (int)floorf(fx);
    float ty = fy - y0, tx = fx - x0;
    int y1 = min(y0 + 1, G - 1), x1 = min(x0 + 1, G - 1);
    stok[idx] = make_int4(y0 * G + x0, y0 * G + x1, y1 * G + x0, y1 * G + x1);
    wco[idx] = make_float4((1.f - ty) * (1.f - tx), (1.f - ty) * tx,
                           ty * (1.f - tx), ty * tx);
  }
}

__global__ void k_img2bf(const float* __restrict__ x, unsigned short* __restrict__ o, int n4) {
  int idx = blockIdx.x * 256 + threadIdx.x;
  if (idx < n4) {
    float4 v = ((const float4*)x)[idx];
    ushort4 r;
    r.x = f2bf(v.x); r.y = f2bf(v.y); r.z = f2bf(v.z); r.w = f2bf(v.w);
    ((ushort4*)o)[idx] = r;
  }
}

__global__ void k_resize_img(const float* __restrict__ x, unsigned short* __restrict__ o,
                             int total) {
  int idx = blockIdx.x * 256 + threadIdx.x;
  if (idx >= total) return;
  int ox = idx % 336;
  int t = idx / 336;
  int oy = t % 336;
  int bc = t / 336;
  const float sc = 447.0f / 335.0f;
  float fy = oy * sc, fx = ox * sc;
  int y0 = (int)floorf(fy), x0 = (int)floorf(fx);
  float ty = fy - y0, tx = fx - x0;
  int y1 = min(y0 + 1, 447), x1 = min(x0 + 1, 447);
  const float* p = x + (size_t)bc * 448 * 448;
  float v00 = p[y0 * 448 + x0], v01 = p[y0 * 448 + x1];
  float v10 = p[y1 * 448 + x0], v11 = p[y1 * 448 + x1];
  float r0 = v00 * (1.f - ty) + v10 * ty;
  float r1 = v01 * (1.f - ty) + v11 * ty;
  o[idx] = f2bf(r0 * (1.f - tx) + r1 * tx);
}

// W [K][N] fp32 -> Wp [N][Kp] bf16 (zero-pad K..Kp), 32x32 LDS tile transpose
__global__ void k_pack_w(const float* __restrict__ W, unsigned short* __restrict__ Wp,
                         int K, int N, int Kp) {
  __shared__ float t[32][33];
  int kb = blockIdx.x * 32, nb = blockIdx.y * 32;
  int tx = threadIdx.x & 31, ty = threadIdx.x >> 5;
#pragma unroll
  for (int r = 0; r < 32; r += 8) {
    int k = kb + ty + r, n = nb + tx;
    t[ty + r][tx] = (k < K) ? W[(size_t)k * N + n] : 0.f;
  }
  __syncthreads();
#pragma unroll
  for (int r = 0; r < 32; r += 8) {
    int n = nb + ty + r, k = kb + tx;
    if (k < Kp) Wp[(size_t)n * Kp + k] = f2bf(t[tx][ty + r]);
  }
}

// ---------------------------------------------------------------- tower GEMM (bf16 MFMA)
// Fp[m][n] = bf16( sum_k xbf[rowoff[m]+koff[k]] * Wp[n][k] + bias[n] )
__global__ __launch_bounds__(256) void k_tower(
    const unsigned short* __restrict__ xbf, const int* __restrict__ rowoff,
    const int* __restrict__ koff, const unsigned short* __restrict__ Wp,
    const float* __restrict__ bias, unsigned short* __restrict__ Fp,
    int M, int N, int K, int Kp, int adma) {
  __shared__ __align__(16) unsigned short As[128 * 32];
  __shared__ __align__(16) unsigned short Bs[128 * 32];
  int tid = threadIdx.x, wave = tid >> 6, lane = tid & 63;
  int n0 = blockIdx.x * 128, m0 = blockIdx.y * 128;

  // B DMA addressing: issue i covers local rows i*64 + (tid>>2), chunk (tid&3)*8 elems
  const unsigned short* wrow0 = Wp + (size_t)(n0 + (tid >> 2)) * Kp + (tid & 3) * 8;
  const unsigned short* wrow1 = wrow0 + (size_t)64 * Kp;
  unsigned short* BsW0 = Bs + wave * 512;
  unsigned short* BsW1 = Bs + 2048 + wave * 512;
  unsigned short* AsW0 = As + wave * 512;
  unsigned short* AsW1 = As + 2048 + wave * 512;

  // scalar-gather ids (adma==0)
  int sm = tid >> 1, skh = (tid & 1) << 4;
  int srow = m0 + sm;
  int sro = (srow < M) ? rowoff[srow] : -1;
  // DMA-gather ids (adma==1; requires koff runs of >=8 aligned: P=32 expert)
  int aro0 = 0, aro1 = 0, ac8 = (tid & 3) << 3;
  if (adma) {
    int am0 = m0 + (tid >> 2);
    int am1 = am0 + 64;
    aro0 = rowoff[(am0 < M) ? am0 : 0];
    aro1 = rowoff[(am1 < M) ? am1 : 0];
  }

  int wm = (wave >> 1) << 6, wn = (wave & 1) << 6;
  int fm = lane & 15, fq = (lane >> 4) << 3;

  f32x4 acc[4][4] = {};

  for (int kb = 0; kb < Kp; kb += 32) {
    unsigned av[8];
    if (!adma) {
      const int* kp = koff + kb + skh;
#pragma unroll
      for (int j = 0; j < 8; ++j) {
        int k0 = kb + skh + 2 * j;
        unsigned lo = (sro >= 0 && k0 < K) ? xbf[sro + kp[2 * j]] : 0u;
        unsigned hi = (sro >= 0 && k0 + 1 < K) ? xbf[sro + kp[2 * j + 1]] : 0u;
        av[j] = lo | (hi << 16);
      }
    }
    __syncthreads();
    gld16(wrow0 + kb, BsW0);
    gld16(wrow1 + kb, BsW1);
    if (adma) {
      int ko = koff[kb + ac8];
      gld16(xbf + aro0 + ko, AsW0);
      gld16(xbf + aro1 + ko, AsW1);
    } else {
      *(uint4*)&As[sm * 32 + skh] = *(const uint4*)&av[0];
      *(uint4*)&As[sm * 32 + skh + 8] = *(const uint4*)&av[4];
    }
    __syncthreads();
    bf16x8 af[4], bfr[4];
#pragma unroll
    for (int i = 0; i < 4; ++i) af[i] = *(const bf16x8*)&As[(wm + i * 16 + fm) * 32 + fq];
#pragma unroll
    for (int j = 0; j < 4; ++j) bfr[j] = *(const bf16x8*)&Bs[(wn + j * 16 + fm) * 32 + fq];
#pragma unroll
    for (int i = 0; i < 4; ++i)
#pragma unroll
      for (int j = 0; j < 4; ++j)
        acc[i][j] = __builtin_amdgcn_mfma_f32_16x16x32_bf16(af[i], bfr[j], acc[i][j], 0, 0, 0);
  }

  int mq = (lane >> 4) << 2;
#pragma unroll
  for (int i = 0; i < 4; ++i) {
    int mbase = m0 + wm + i * 16 + mq;
#pragma unroll
    for (int j = 0; j < 4; ++j) {
      int n = n0 + wn + j * 16 + fm;
      float bsv = bias[n];
      f32x4 v = acc[i][j];
#pragma unroll
      for (int r = 0; r < 4; ++r) {
        int mm = mbase + r;
        if (mm < M) Fp[(size_t)mm * N + n] = f2bf(v[r] + bsv);
      }
    }
  }
}

// ---------------------------------------------------------------- feature-grid resize (bf16)
__global__ void k_feat_resize(const unsigned short* __restrict__ C1,
                              unsigned short* __restrict__ F,
                              const int4* __restrict__ stok, const float4* __restrict__ wco,
                              int Tsrc, int C) {
  int bt = blockIdx.x;
  int bl = bt >> 10, t = bt & 1023;
  int4 s = stok[t];
  float4 w = wco[t];
  const unsigned* b32 = (const unsigned*)(C1 + (size_t)bl * Tsrc * C);
  unsigned* o32 = (unsigned*)(F + (size_t)bt * C);
  int C2 = C >> 1;
  int r0 = s.x * C2, r1 = s.y * C2, r2 = s.z * C2, r3 = s.w * C2;
  for (int c = threadIdx.x; c < C2; c += 256) {
    unsigned p0 = b32[r0 + c], p1 = b32[r1 + c], p2 = b32[r2 + c], p3 = b32[r3 + c];
    float lo = w.x * bf2f(p0 & 0xffffu) + w.y * bf2f(p1 & 0xffffu) +
               w.z * bf2f(p2 & 0xffffu) + w.w * bf2f(p3 & 0xffffu);
    float hi = w.x * bf2f(p0 >> 16) + w.y * bf2f(p1 >> 16) +
               w.z * bf2f(p2 >> 16) + w.w * bf2f(p3 >> 16);
    o32[c] = (unsigned)f2bf(lo) | ((unsigned)f2bf(hi) << 16);
  }
}

// ---------------------------------------------------------------- projector GEMM (bf16 MFMA)
// mode 0: out = wgt*(A@W + bias)   (zero-fills when wgt==0)
// mode 1: out += wgt*(A@W + bias)  (returns when wgt==0)
__global__ __launch_bounds__(256) void k_proj(
    const unsigned short* __restrict__ Ap, const unsigned short* __restrict__ Wp,
    const float* __restrict__ bias, float* __restrict__ out,
    const float* __restrict__ w3, int b0, int e, int K, int mode) {
  __shared__ __align__(16) unsigned short As[128 * 32];
  __shared__ __align__(16) unsigned short Bs[128 * 32];
  int tid = threadIdx.x, wave = tid >> 6, lane = tid & 63;
  int n0 = blockIdx.x * 128, m0 = blockIdx.y * 128;
  float wgt = w3[(b0 + (m0 >> 10)) * 3 + e];
  float* obase = out + ((size_t)b0 * 1024 + (size_t)m0) * HID + n0;
  if (wgt == 0.f) {
    if (mode == 0) {
      float4 z = make_float4(0.f, 0.f, 0.f, 0.f);
      for (int idx = tid; idx < 128 * 32; idx += 256) {
        int rr = idx >> 5, cc = (idx & 31) << 2;
        *(float4*)&obase[(size_t)rr * HID + cc] = z;
      }
    }
    return;
  }
  const unsigned short* arow0 = Ap + (size_t)(m0 + (tid >> 2)) * K + (tid & 3) * 8;
  const unsigned short* arow1 = arow0 + (size_t)64 * K;
  const unsigned short* wrow0 = Wp + (size_t)(n0 + (tid >> 2)) * K + (tid & 3) * 8;
  const unsigned short* wrow1 = wrow0 + (size_t)64 * K;
  unsigned short* AsW0 = As + wave * 512;
  unsigned short* AsW1 = As + 2048 + wave * 512;
  unsigned short* BsW0 = Bs + wave * 512;
  unsigned short* BsW1 = Bs + 2048 + wave * 512;

  int wm = (wave >> 1) << 6, wn = (wave & 1) << 6;
  int fm = lane & 15, fq = (lane >> 4) << 3;
  f32x4 acc[4][4] = {};

  for (int kb = 0; kb < K; kb += 32) {
    __syncthreads();
    gld16(arow0 + kb, AsW0);
    gld16(arow1 + kb, AsW1);
    gld16(wrow0 + kb, BsW0);
    gld16(wrow1 + kb, BsW1);
    __syncthreads();
    bf16x8 af[4], bfr[4];
#pragma unroll
    for (int i = 0; i < 4; ++i) af[i] = *(const bf16x8*)&As[(wm + i * 16 + fm) * 32 + fq];
#pragma unroll
    for (int j = 0; j < 4; ++j) bfr[j] = *(const bf16x8*)&Bs[(wn + j * 16 + fm) * 32 + fq];
#pragma unroll
    for (int i = 0; i < 4; ++i)
#pragma unroll
      for (int j = 0; j < 4; ++j)
        acc[i][j] = __builtin_amdgcn_mfma_f32_16x16x32_bf16(af[i], bfr[j], acc[i][j], 0, 0, 0);
  }

  int mq = (lane >> 4) << 2;
#pragma unroll
  for (int i = 0; i < 4; ++i) {
#pragma unroll
    for (int j = 0; j < 4; ++j) {
      int n = wn + j * 16 + fm;
      float bsv = bias[n0 + n];
      f32x4 v = acc[i][j];
#pragma unroll
      for (int r = 0; r < 4; ++r) {
        float val = wgt * (v[r] + bsv);
        float* op = &obase[(size_t)(wm + i * 16 + mq + r) * HID + n];
        if (mode == 0) *op = val;
        else *op += val;
      }
    }
  }
}

// ---------------------------------------------------------------- launch
extern "C" void kernel_launch(void* const* d_in, const int* in_sizes, int n_in,
                              void* d_out, int out_size, void* d_ws, size_t ws_size,
                              hipStream_t stream) {
  (void)in_sizes; (void)n_in; (void)out_size;
  const float* x = (const float*)d_in[0];
  const int* sel = (const int*)d_in[1];
  const float* rw = (const float*)d_in[2];
  const float* wt[3] = {(const float*)d_in[3], (const float*)d_in[7], (const float*)d_in[11]};
  const float* bt[3] = {(const float*)d_in[4], (const float*)d_in[8], (const float*)d_in[12]};
  const float* wp[3] = {(const float*)d_in[5], (const float*)d_in[9], (const float*)d_in[13]};
  const float* bp[3] = {(const float*)d_in[6], (const float*)d_in[10], (const float*)d_in[14]};
  float* out = (float*)d_out;

  char* ws = (char*)d_ws;
  size_t off = 0;
  auto alloc = [&](size_t bytes) -> void* {
    off = (off + 255) & ~(size_t)255;
    void* p = ws + off;
    off += bytes;
    return p;
  };

  float* w3 = (float*)alloc(64 * 3 * 4);
  int* koff0 = (int*)alloc(608 * 4);
  int* koff1 = (int*)alloc(608 * 4);
  int* koff2 = (int*)alloc(3072 * 4);
  int* ro0 = (int*)alloc((size_t)64 * 1024 * 4);
  int* ro1 = (int*)alloc((size_t)64 * 576 * 4);
  int* ro2 = (int*)alloc((size_t)64 * 196 * 4);
  int4* st1 = (int4*)alloc(1024 * 16);
  float4* wc1 = (float4*)alloc(1024 * 16);
  int4* st2 = (int4*)alloc(1024 * 16);
  float4* wc2 = (float4*)alloc(1024 * 16);
  unsigned short* wt0p = (unsigned short*)alloc((size_t)1024 * 608 * 2);
  unsigned short* wt1p = (unsigned short*)alloc((size_t)768 * 608 * 2);
  unsigned short* wt2p = (unsigned short*)alloc((size_t)1152 * 3072 * 2);
  unsigned short* wp0p = (unsigned short*)alloc((size_t)1024 * 1024 * 2);
  unsigned short* wp1p = (unsigned short*)alloc((size_t)1024 * 768 * 2);
  unsigned short* wp2p = (unsigned short*)alloc((size_t)1024 * 1152 * 2);
  const size_t NIMG = (size_t)64 * 3 * 448 * 448;  // 38,535,168
  unsigned short* xbf = (unsigned short*)alloc(NIMG * 2);
  size_t fixed_end = off;

  const size_t per_b = ((size_t)3 * 336 * 336 + (size_t)1024 * 1024 + (size_t)1024 * 1152) * 2;
  int bch = 64;
  while (bch > 1 && fixed_end + (size_t)bch * per_b + 65536 > ws_size) bch >>= 1;
  unsigned short* x336bf = (unsigned short*)alloc((size_t)bch * 3 * 336 * 336 * 2);
  unsigned short* Ftow = (unsigned short*)alloc((size_t)bch * 1024 * 1024 * 2);
  unsigned short* Fres = (unsigned short*)alloc((size_t)bch * 1024 * 1152 * 2);

  // ---- prep
  k_weights<<<1, 64, 0, stream>>>(sel, rw, w3);
  k_img2bf<<<(int)((NIMG / 4 + 255) / 256), 256, 0, stream>>>(x, xbf, (int)(NIMG / 4));
  {
    int n0 = max(608, max(bch * 1024, 1024));
    int n1 = max(608, max(bch * 576, 1024));
    int n2 = max(3072, max(bch * 196, 1024));
    k_tables<<<(n0 + 255) / 256, 256, 0, stream>>>(koff0, ro0, st1, wc1, 448, 14, 32, 1024, bch, 588, 608);
    k_tables<<<(n1 + 255) / 256, 256, 0, stream>>>(koff1, ro1, st1, wc1, 336, 14, 24, 576, bch, 588, 608);
    k_tables<<<(n2 + 255) / 256, 256, 0, stream>>>(koff2, ro2, st2, wc2, 448, 32, 14, 196, bch, 3072, 3072);
  }
  k_pack_w<<<dim3(608 / 32, 1024 / 32), 256, 0, stream>>>(wt[0], wt0p, 588, 1024, 608);
  k_pack_w<<<dim3(608 / 32, 768 / 32), 256, 0, stream>>>(wt[1], wt1p, 588, 768, 608);
  k_pack_w<<<dim3(3072 / 32, 1152 / 32), 256, 0, stream>>>(wt[2], wt2p, 3072, 1152, 3072);
  k_pack_w<<<dim3(1024 / 32, 1024 / 32), 256, 0, stream>>>(wp[0], wp0p, 1024, 1024, 1024);
  k_pack_w<<<dim3(768 / 32, 1024 / 32), 256, 0, stream>>>(wp[1], wp1p, 768, 1024, 768);
  k_pack_w<<<dim3(1152 / 32, 1024 / 32), 256, 0, stream>>>(wp[2], wp2p, 1152, 1024, 1152);

  int nchunk = 64 / bch;
  for (int c = 0; c < nchunk; ++c) {
    int b0 = c * bch;
    const unsigned short* xc = xbf + (size_t)b0 * 3 * 448 * 448;
    dim3 gp(HID / 128, bch * 1024 / 128);

    // ---- Expert 0
    {
      int M = bch * 1024;
      dim3 g(1024 / 128, M / 128);
      k_tower<<<g, 256, 0, stream>>>(xc, ro0, koff0, wt0p, bt[0], Ftow, M, 1024, 588, 608, 0);
      k_proj<<<gp, 256, 0, stream>>>(Ftow, wp0p, bp[0], out, w3, b0, 0, 1024, 0);
    }
    // ---- Expert 1
    {
      int tot = bch * 3 * 336 * 336;
      k_resize_img<<<(tot + 255) / 256, 256, 0, stream>>>(x + (size_t)b0 * 3 * 448 * 448, x336bf, tot);
      int M = bch * 576;
      dim3 g(768 / 128, (M + 127) / 128);
      k_tower<<<g, 256, 0, stream>>>(x336bf, ro1, koff1, wt1p, bt[1], Ftow, M, 768, 588, 608, 0);
      k_feat_resize<<<bch * 1024, 256, 0, stream>>>(Ftow, Fres, st1, wc1, 576, 768);
      k_proj<<<gp, 256, 0, stream>>>(Fres, wp1p, bp[1], out, w3, b0, 1, 768, 1);
    }
    // ---- Expert 2 (P=32 -> A staging via global_load_lds)
    {
      int M = bch * 196;
      dim3 g(1152 / 128, (M + 127) / 128);
      k_tower<<<g, 256, 0, stream>>>(xc, ro2, koff2, wt2p, bt[2], Ftow, M, 1152, 3072, 3072, 1);
      k_feat_resize<<<bch * 1024, 256, 0, stream>>>(Ftow, Fres, st2, wc2, 196, 1152);
      k_proj<<<gp, 256, 0, stream>>>(Fres, wp2p, bp[2], out, w3, b0, 2, 1152, 1);
    }
  }
}